// Round 7
// baseline (246.510 us; speedup 1.0000x reference)
//
#include <hip/hip_runtime.h>
#include <hip/hip_bf16.h>
#include <math.h>

typedef __bf16 bf16;
typedef __attribute__((ext_vector_type(8))) __bf16 bf16x8;
typedef __attribute__((ext_vector_type(4))) __bf16 bf16x4;
typedef __attribute__((ext_vector_type(4))) float floatx4;
typedef __attribute__((ext_vector_type(16))) float floatx16;

#define BB 2
#define NN 2048
#define LL 2048
#define DD 1024
#define HH 16
#define HDD 64

// Q pre-scale: HD^-0.5 * log2(e) -> scores in log2 units
#define QSCALE (0.125f * 1.44269504f)
#define PCLAMP 21.66f
#define MBIAS  (-100000.0f)

// async global->LDS, 16B per lane. LDS dest must be wave-uniform + lane*16.
__device__ __forceinline__ void async16(const bf16* g, bf16* l) {
  __builtin_amdgcn_global_load_lds((const __attribute__((address_space(1))) void*)(g),
                                   (__attribute__((address_space(3))) void*)(l), 16, 0, 0);
}

// v_cvt_pk_bf16_f32: pack two f32 -> u32 of {lo=bf16(a), hi=bf16(b)}
__device__ __forceinline__ unsigned cvtpk(float a, float b) {
  unsigned r;
  asm("v_cvt_pk_bf16_f32 %0, %1, %2" : "=v"(r) : "v"(a), "v"(b));
  return r;
}

// permlane32_swap: x'[0:31]=x[0:31], x'[32+j]=y[j]; y'[j]=x[32+j], y'[32:63]=y[32:63]
__device__ __forceinline__ void plswap(unsigned &x, unsigned &y) {
  auto r = __builtin_amdgcn_permlane32_swap(x, y, false, false);
  x = (unsigned)r[0];
  y = (unsigned)r[1];
}

__device__ __forceinline__ bf16x8 mk_frag(unsigned w0, unsigned w1, unsigned w2, unsigned w3) {
  union { unsigned u[4]; bf16x8 b; } f;
  f.u[0] = w0; f.u[1] = w1; f.u[2] = w2; f.u[3] = w3;
  return f.b;
}

// ---------------------------------------------------------------------------
// Fused prep: [0,nconv) f32->bf16 converts (two inputs, nconv/2 blocks each),
// [nconv, nconv+1024) W-transpose tiles (4 matrices), [nconv+1024] mask ->
// biasF floats (dtype auto-detect: int32 {0,1} / bytes / f32 {0,1}).
// ---------------------------------------------------------------------------
__global__ __launch_bounds__(256) void prep_kernel(
    const float* __restrict__ xq, const float* __restrict__ xkv,
    bf16* __restrict__ Xqb, bf16* __restrict__ Xkvb, int nconv, int elemsEach,
    const float* __restrict__ W0, const float* __restrict__ W1,
    const float* __restrict__ W2, const float* __restrict__ W3,
    bf16* __restrict__ T0, bf16* __restrict__ T1,
    bf16* __restrict__ T2, bf16* __restrict__ T3,
    const unsigned* __restrict__ mask, float* __restrict__ biasF)
{
  __shared__ bf16 Tb[64][72];
  const int bid = blockIdx.x;
  const int t = threadIdx.x;

  if (bid < nconv) {
    const int half = nconv >> 1;
    const float* s = (bid < half) ? xq : xkv;
    bf16* d = (bid < half) ? Xqb : Xkvb;
    int gid = (bid < half) ? bid : bid - half;
    int idx = (gid * 256 + t) * 8;
    if (idx >= elemsEach) return;
    floatx4 a = *(const floatx4*)&s[idx];
    floatx4 b = *(const floatx4*)&s[idx + 4];
    bf16x8 o;
#pragma unroll
    for (int e = 0; e < 4; e++) { o[e] = (bf16)a[e]; o[4 + e] = (bf16)b[e]; }
    *(bf16x8*)&d[idx] = o;
    return;
  }
  if (bid < nconv + 1024) {
    const int wb = bid - nconv;
    const int which = wb >> 8;
    const float* W = which == 0 ? W0 : which == 1 ? W1 : which == 2 ? W2 : W3;
    bf16*       T = which == 0 ? T0 : which == 1 ? T1 : which == 2 ? T2 : T3;
    const int tile = wb & 255;
    const int k0 = (tile >> 4) * 64, n0 = (tile & 15) * 64;
    const int r = t >> 2;
    const int c = (t & 3) * 16;
    const float* Wr = W + (size_t)(k0 + r) * 1024 + n0 + c;
    floatx4 f0 = *(const floatx4*)(Wr + 0);
    floatx4 f1 = *(const floatx4*)(Wr + 4);
    floatx4 f2 = *(const floatx4*)(Wr + 8);
    floatx4 f3 = *(const floatx4*)(Wr + 12);
#pragma unroll
    for (int e = 0; e < 4; e++) {
      Tb[c + e][r]      = (bf16)f0[e];
      Tb[c + 4 + e][r]  = (bf16)f1[e];
      Tb[c + 8 + e][r]  = (bf16)f2[e];
      Tb[c + 12 + e][r] = (bf16)f3[e];
    }
    __syncthreads();
    bf16* Tr = T + (size_t)(n0 + r) * 1024 + k0 + c;
    *(bf16x8*)&Tr[0] = *(const bf16x8*)&Tb[r][c];
    *(bf16x8*)&Tr[8] = *(const bf16x8*)&Tb[r][c + 8];
    return;
  }
  // mask -> biasF (one block)
  __shared__ int hasBig, hasFloat;
  if (t == 0) { hasBig = 0; hasFloat = 0; }
  __syncthreads();
  int big = 0, flt = 0;
  for (int idx = t; idx < 1024; idx += 256) {
    unsigned v = mask[idx];
    if (v == 0x3F800000u) flt = 1;
    else if (v > 1u) big = 1;
  }
  if (big) atomicOr(&hasBig, 1);
  if (flt) atomicOr(&hasFloat, 1);
  __syncthreads();
  const int mode = hasFloat ? 2 : (hasBig ? 1 : 0);
  for (int k = t * 16; k < t * 16 + 16; k++) {
    bool m;
    if (mode == 0)      m = ((const int*)mask)[k] != 0;
    else if (mode == 1) m = ((const unsigned char*)mask)[k] != 0;
    else                m = ((const float*)mask)[k] != 0.0f;
    biasF[k] = m ? MBIAS : 0.0f;
  }
}

// ---------------------------------------------------------------------------
// qkv GEMM body v3: 128x128 tile, BK=32, 32x32x16 MFMAs; 4-slot LDS rotation,
// 2-ahead counted-vmcnt pipeline, stage issued AFTER the barrier.
// Slot audit: stage(k+3) writes slot (k+3)&3 = tile (k-1)'s slot; issued
// post-barrier of iter k, and ALL waves finished reading tile k-1 before
// that barrier -> safe. vmcnt before barrier allows the 2 newest stages
// (8 loads) to stay in flight; tail 8->4->0.
// One GEMM per launch (which passed by host): per-XCD working set =
// 4 A-panels + 8 B-panels = 3 MB < 4 MB L2 (the fused 3-GEMM launch had
// 9 MB/XCD -> L2 thrash -> HBM panel re-reads ~384 MB).
// Chunk swizzle: global chunk c of row r at LDS slot c^((r>>1)&3).
// transv: write bf16 V^T globally as Vt[b][col][key].
// ---------------------------------------------------------------------------
template <typename TC>
__device__ __forceinline__ void gemm_body32(
    int bx, const bf16* __restrict__ A, const bf16* __restrict__ Wt,
    const float* __restrict__ bias, TC* __restrict__ C, float scale, int transv)
{
  __shared__ bf16 As[4][128 * 32];
  __shared__ bf16 Bs[4][128 * 32];

  const int tm = bx >> 3, tn = bx & 7;
  const int m0 = tm * 128, n0 = tn * 128;
  const int t = threadIdx.x;
  const int w = t >> 6, l = t & 63;
  const int col = l & 31, half = l >> 5;
  const int wm = (w >> 1) * 64, wn = (w & 1) * 64;
  const int sr  = t >> 2;                          // dest row 0..63
  const int scl = (t & 3) * 8;                     // linear LDS chunk (elems)
  const int scs = (((t & 3) ^ ((t >> 3) & 3)) * 8); // swizzled global chunk
  const int csw = (col >> 1) & 3;                  // frag de-swizzle key

  floatx16 acc[2][2];
#pragma unroll
  for (int mi = 0; mi < 2; mi++)
#pragma unroll
    for (int ni = 0; ni < 2; ni++)
#pragma unroll
      for (int e = 0; e < 16; e++) acc[mi][ni][e] = 0.0f;

  auto STAGE = [&](int k0, int s) {
    async16(&A[(size_t)(m0 + sr) * 1024 + k0 + scs],       &As[s][sr * 32 + scl]);
    async16(&A[(size_t)(m0 + 64 + sr) * 1024 + k0 + scs],  &As[s][(64 + sr) * 32 + scl]);
    async16(&Wt[(size_t)(n0 + sr) * 1024 + k0 + scs],      &Bs[s][sr * 32 + scl]);
    async16(&Wt[(size_t)(n0 + 64 + sr) * 1024 + k0 + scs], &Bs[s][(64 + sr) * 32 + scl]);
  };

  STAGE(0, 0);
  STAGE(32, 1);
  STAGE(64, 2);
  const int NK = 1024 / 32;  // 32
  for (int k = 0; k < NK; k++) {
    // allow the 2 newest stages (k+1, k+2) to stay in flight; drain stage(k)
    if (k + 3 <= NK - 1)      asm volatile("s_waitcnt vmcnt(8)" ::: "memory");
    else if (k + 2 <= NK - 1) asm volatile("s_waitcnt vmcnt(8)" ::: "memory");
    else if (k + 1 <= NK - 1) asm volatile("s_waitcnt vmcnt(4)" ::: "memory");
    else                      asm volatile("s_waitcnt vmcnt(0)" ::: "memory");
    __builtin_amdgcn_s_barrier();
    __builtin_amdgcn_sched_barrier(0);
    if (k + 3 < NK) STAGE((k + 3) * 32, (k + 3) & 3);  // post-barrier: slot free
    const bf16* as = &As[k & 3][0];
    const bf16* bs = &Bs[k & 3][0];
#pragma unroll
    for (int kk = 0; kk < 2; kk++) {
      const int ch = ((kk * 2 + half) ^ csw) * 8;  // de-swizzled chunk offset
      bf16x8 af[2], bfr[2];
#pragma unroll
      for (int mi = 0; mi < 2; mi++)
        af[mi] = *(const bf16x8*)&as[(wm + mi * 32 + col) * 32 + ch];
#pragma unroll
      for (int ni = 0; ni < 2; ni++)
        bfr[ni] = *(const bf16x8*)&bs[(wn + ni * 32 + col) * 32 + ch];
#pragma unroll
      for (int mi = 0; mi < 2; mi++)
#pragma unroll
        for (int ni = 0; ni < 2; ni++)
          acc[mi][ni] = __builtin_amdgcn_mfma_f32_32x32x16_bf16(af[mi], bfr[ni], acc[mi][ni], 0, 0, 0);
    }
  }
  // 32x32 C/D layout: col = lane&31, row = (reg&3) + 8*(reg>>2) + 4*(lane>>5)
#pragma unroll
  for (int ni = 0; ni < 2; ni++) {
    int colg = n0 + wn + ni * 32 + col;
    float bv = bias[colg];
#pragma unroll
    for (int mi = 0; mi < 2; mi++) {
      int rbase = m0 + wm + mi * 32 + half * 4;
      if (transv) {
#pragma unroll
        for (int g = 0; g < 4; g++) {
          int key0 = rbase + g * 8;
          int bb = key0 >> 11, key = key0 & 2047;
          bf16x4 v4;
#pragma unroll
          for (int r = 0; r < 4; r++) v4[r] = (bf16)(acc[mi][ni][g * 4 + r] + bv);
          *(bf16x4*)&((bf16*)C)[(size_t)bb * (DD * (size_t)LL) + (size_t)colg * LL + key] = v4;
        }
      } else {
#pragma unroll
        for (int g = 0; g < 4; g++)
#pragma unroll
          for (int r = 0; r < 4; r++)
            C[(size_t)(rbase + g * 8 + r) * 1024 + colg] = (TC)((acc[mi][ni][g * 4 + r] + bv) * scale);
      }
    }
  }
}

// One projection GEMM per launch (grid = 1<<shift); which selects Q/K/V.
// XCD-bijective swizzle: each XCD gets 4 contiguous tm panels x all tn.
__global__ __launch_bounds__(256) void qkv_gemm32(
    const bf16* __restrict__ Xq, const bf16* __restrict__ Xkv,
    const bf16* __restrict__ Wtq, const bf16* __restrict__ Wtk, const bf16* __restrict__ Wtv,
    const float* __restrict__ bq, const float* __restrict__ bk, const float* __restrict__ bv,
    bf16* __restrict__ Qp, bf16* __restrict__ Kp, bf16* __restrict__ VtG, int shift, int which)
{
  const int bid = blockIdx.x;
  const int q = (1 << shift) >> 3;
  const int bx = (bid & 7) * q + (bid >> 3);   // XCD-contiguous tm ranges
  if (which == 0)      gemm_body32<bf16>(bx, Xq,  Wtq, bq, Qp,  QSCALE, 0);
  else if (which == 1) gemm_body32<bf16>(bx, Xkv, Wtk, bk, Kp,  1.0f,   0);
  else                 gemm_body32<bf16>(bx, Xkv, Wtv, bv, VtG, 1.0f,   1);
}

// ---------------------------------------------------------------------------
// out GEMM v3: 128x64 tile, BK=32, 16x16x32 MFMAs; 4-slot 2-ahead pipeline,
// stage issued post-barrier (same audit as qkv). 48 KB LDS -> 2 blocks/CU.
// ---------------------------------------------------------------------------
__global__ __launch_bounds__(256) void out_gemm(
    const bf16* __restrict__ A, const bf16* __restrict__ Wt,
    const float* __restrict__ bias, float* __restrict__ C)
{
  __shared__ bf16 As[4][128 * 32];
  __shared__ bf16 Bs[4][64 * 32];

  const int bid = blockIdx.x;
  const int qs = gridDim.x >> 3;
  const int bx = (bid & 7) * qs + (bid >> 3);  // XCD-bijective swizzle
  const int tm = bx >> 4, tn = bx & 15;
  const int m0 = tm * 128, n0 = tn * 64;
  const int t = threadIdx.x;
  const int w = t >> 6, l = t & 63;
  const int q = l >> 4, i = l & 15;
  const int wm = (w >> 1) * 64, wn = (w & 1) * 32;
  const int sr  = t >> 2;
  const int scl = (t & 3) * 8;
  const int scs = (((t & 3) ^ ((t >> 3) & 3)) * 8);
  const int isw = (i >> 1) & 3;

  const floatx4 zero = {0.f, 0.f, 0.f, 0.f};
  floatx4 acc[4][2];
#pragma unroll
  for (int mi = 0; mi < 4; mi++)
#pragma unroll
    for (int ni = 0; ni < 2; ni++) acc[mi][ni] = zero;

  auto STAGE = [&](int k0, int s) {
    async16(&A[(size_t)(m0 + sr) * 1024 + k0 + scs],       &As[s][sr * 32 + scl]);
    async16(&A[(size_t)(m0 + 64 + sr) * 1024 + k0 + scs],  &As[s][(64 + sr) * 32 + scl]);
    async16(&Wt[(size_t)(n0 + sr) * 1024 + k0 + scs],      &Bs[s][sr * 32 + scl]);
  };

  STAGE(0, 0);
  STAGE(32, 1);
  STAGE(64, 2);
  const int NK = 1024 / 32;
  for (int k = 0; k < NK; k++) {
    if (k + 2 <= NK - 1)      asm volatile("s_waitcnt vmcnt(6)" ::: "memory");
    else if (k + 1 <= NK - 1) asm volatile("s_waitcnt vmcnt(3)" ::: "memory");
    else                      asm volatile("s_waitcnt vmcnt(0)" ::: "memory");
    __builtin_amdgcn_s_barrier();
    __builtin_amdgcn_sched_barrier(0);
    if (k + 3 < NK) STAGE((k + 3) * 32, (k + 3) & 3);
    const bf16* as = &As[k & 3][0];
    const bf16* bs = &Bs[k & 3][0];
    const int ch = (q ^ isw) * 8;
    bf16x8 af[4], bfr[2];
#pragma unroll
    for (int mi = 0; mi < 4; mi++)
      af[mi] = *(const bf16x8*)&as[(wm + mi * 16 + i) * 32 + ch];
#pragma unroll
    for (int ni = 0; ni < 2; ni++)
      bfr[ni] = *(const bf16x8*)&bs[(wn + ni * 16 + i) * 32 + ch];
#pragma unroll
    for (int mi = 0; mi < 4; mi++)
#pragma unroll
      for (int ni = 0; ni < 2; ni++)
        acc[mi][ni] = __builtin_amdgcn_mfma_f32_16x16x32_bf16(af[mi], bfr[ni], acc[mi][ni], 0, 0, 0);
  }
#pragma unroll
  for (int ni = 0; ni < 2; ni++) {
    int colg = n0 + wn + ni * 16 + i;
    float bv = bias[colg];
#pragma unroll
    for (int mi = 0; mi < 4; mi++) {
      int row = m0 + wm + mi * 16 + q * 4;
#pragma unroll
      for (int r = 0; r < 4; r++)
        C[(size_t)(row + r) * 1024 + colg] = acc[mi][ni][r] + bv;
    }
  }
}

// ---------------------------------------------------------------------------
// Flash attention v5 (frozen at 62 us / 1.11 PF): counted-vmcnt pipeline,
// cross-tile QK(t)/PV(t-1)/softmax(t), in-register P transpose
// (cvt_pk + permlane32_swap), 32x32x16 MFMAs, fixed-max softmax in log2
// units, XOR-chunk-swizzled K/V staging, 4-slot LDS rotation.
// ---------------------------------------------------------------------------
__global__ __launch_bounds__(256) void attn_kernel(
    const bf16* __restrict__ Q, const bf16* __restrict__ K,
    const bf16* __restrict__ Vt, const float* __restrict__ biasF,
    bf16* __restrict__ O, int hbits)
{
  __shared__ bf16 Kbuf[4][64 * 64];
  __shared__ bf16 Vbuf[4][64 * 64];

  const int bid = blockIdx.x;
  const int qt = bid >> hbits;
  const int hb = bid & ((1 << hbits) - 1);
  const int h  = (hbits == 5) ? (hb >> 1) : hb;
  const int b  = (hbits == 5) ? (hb & 1) : 0;
  const int t = threadIdx.x;
  const int w = t >> 6, lane = t & 63;
  const int col = lane & 31;     // qrow within wave / MFMA col
  const int hi  = lane >> 5;
  const int lsw = lane & 7;      // fragment de-swizzle key

  const bf16* Qb = Q  + (size_t)b * (NN * DD) + h * HDD;
  const bf16* Kb = K  + (size_t)b * (LL * DD) + h * HDD;
  const bf16* Vb = Vt + (size_t)b * (DD * (size_t)LL) + (size_t)(h * HDD) * LL;
  const float* biasFb = biasF + b * LL;

  const int qrow = qt * 128 + w * 32;

  // Q fragment: B[col=qrow][k=d], k = dc*16 + hi*8 + e
  bf16x8 qfrag[4];
#pragma unroll
  for (int dc = 0; dc < 4; dc++)
    qfrag[dc] = *(const bf16x8*)&Qb[(size_t)(qrow + col) * DD + dc * 16 + hi * 8];

  floatx16 oacc[2];
#pragma unroll
  for (int db = 0; db < 2; db++)
#pragma unroll
    for (int e = 0; e < 16; e++) oacc[db][e] = 0.0f;
  float psum = 0.0f;

  // staging indices
  const int sr  = t >> 3;                       // dest row 0..31
  const int scl = (t & 7) * 8;                  // linear LDS chunk (elems)
  const int scs = ((t & 7) ^ (sr & 7)) * 8;     // swizzled global chunk (elems)

  auto STAGE = [&](int tile, int slot) {
    const int k0 = tile * 64;
    async16(&Kb[(size_t)(k0 + sr) * DD + scs],        &Kbuf[slot][sr * 64 + scl]);
    async16(&Kb[(size_t)(k0 + sr + 32) * DD + scs],   &Kbuf[slot][(sr + 32) * 64 + scl]);
    async16(&Vb[(size_t)sr * LL + k0 + scs],          &Vbuf[slot][sr * 64 + scl]);
    async16(&Vb[(size_t)(sr + 32) * LL + k0 + scs],   &Vbuf[slot][(sr + 32) * 64 + scl]);
  };

  floatx4 pb[2][4];      // bias for the CURRENT tile (C-init of QK)
  bf16x8 pfp[4];         // P fragments of the PREVIOUS tile (PV input)
  floatx16 sacc[2];

  auto QK = [&](int slot) {
#pragma unroll
    for (int kb = 0; kb < 2; kb++)
#pragma unroll
      for (int g = 0; g < 4; g++)
#pragma unroll
        for (int rr = 0; rr < 4; rr++)
          sacc[kb][g * 4 + rr] = pb[kb][g][rr];
    __builtin_amdgcn_s_setprio(1);
#pragma unroll
    for (int kb = 0; kb < 2; kb++)
#pragma unroll
      for (int dc = 0; dc < 4; dc++) {
        bf16x8 kf = *(const bf16x8*)&Kbuf[slot][(kb * 32 + col) * 64 + ((dc * 2 + hi) ^ lsw) * 8];
        sacc[kb] = __builtin_amdgcn_mfma_f32_32x32x16_bf16(kf, qfrag[dc], sacc[kb], 0, 0, 0);
      }
  };

  auto PV = [&](int slot) {
#pragma unroll
    for (int db = 0; db < 2; db++)
#pragma unroll
      for (int kc = 0; kc < 4; kc++) {
        bf16x8 vf = *(const bf16x8*)&Vbuf[slot][(db * 32 + col) * 64 + ((kc * 2 + hi) ^ lsw) * 8];
        oacc[db] = __builtin_amdgcn_mfma_f32_32x32x16_bf16(vf, pfp[kc], oacc[db], 0, 0, 0);
      }
    __builtin_amdgcn_s_setprio(0);
  };

  // softmax on sacc -> pfp (P fragments for next iter's PV); prefetch bias
  auto SOFTMAX = [&](int nextTile) {
#pragma unroll
    for (int kb = 0; kb < 2; kb++)
#pragma unroll
      for (int hh = 0; hh < 2; hh++) {
        float pv[8];
#pragma unroll
        for (int e = 0; e < 8; e++) {
          float p = __builtin_amdgcn_exp2f(fminf(sacc[kb][hh * 8 + e], PCLAMP));
          psum += p;
          pv[e] = p;
        }
        unsigned a0 = cvtpk(pv[0], pv[1]);
        unsigned a1 = cvtpk(pv[2], pv[3]);
        unsigned b0 = cvtpk(pv[4], pv[5]);
        unsigned b1 = cvtpk(pv[6], pv[7]);
        plswap(a0, b0);
        plswap(a1, b1);
        pfp[kb * 2 + hh] = mk_frag(a0, a1, b0, b1);
      }
    const int kn = (nextTile & 31) * 64;
#pragma unroll
    for (int kb = 0; kb < 2; kb++)
#pragma unroll
      for (int g = 0; g < 4; g++)
        pb[kb][g] = *(const floatx4*)&biasFb[kn + kb * 32 + g * 8 + hi * 4];
  };

  // prologue: tile-0 bias first (oldest vmem), then stage tiles 0,1
#pragma unroll
  for (int kb = 0; kb < 2; kb++)
#pragma unroll
    for (int g = 0; g < 4; g++)
      pb[kb][g] = *(const floatx4*)&biasFb[kb * 32 + g * 8 + hi * 4];
  STAGE(0, 0);
  STAGE(1, 1);

  asm volatile("s_waitcnt vmcnt(4)" ::: "memory");
  __builtin_amdgcn_s_barrier();
  __builtin_amdgcn_sched_barrier(0);

  // iteration 0 (peeled: no PV yet)
  QK(0);
  __builtin_amdgcn_s_setprio(0);
  SOFTMAX(1);

  const int NT = LL / 64;  // 32
  for (int kt = 1; kt < NT; kt++) {
    if (kt + 1 < NT) {
      STAGE(kt + 1, (kt + 1) & 3);
      asm volatile("s_waitcnt vmcnt(4)" ::: "memory");
    } else {
      asm volatile("s_waitcnt vmcnt(0)" ::: "memory");
    }
    __builtin_amdgcn_s_barrier();
    __builtin_amdgcn_sched_barrier(0);
    QK(kt & 3);          // sacc for tile kt (prio 1 from inside QK)
    PV((kt - 1) & 3);    // consumes pfp (tile kt-1); prio back to 0 after
    SOFTMAX(kt + 1);     // pfp <- tile kt; prefetch bias kt+1
  }
  // epilogue: PV for the last tile
  __builtin_amdgcn_s_setprio(1);
  PV((NT - 1) & 3);

  // lanes l and l+32 share qrow and jointly hold all keys
  psum += __shfl_xor(psum, 32, 64);
  float inv = 1.0f / fmaxf(psum, 1e-30f);

  bf16* Ob = O + (size_t)b * (NN * DD) + h * HDD;
#pragma unroll
  for (int db = 0; db < 2; db++)
#pragma unroll
    for (int g = 0; g < 4; g++) {
      bf16x4 v4;
#pragma unroll
      for (int rr = 0; rr < 4; rr++) v4[rr] = (bf16)(oacc[db][g * 4 + rr] * inv);
      *(bf16x4*)&Ob[(size_t)(qrow + col) * DD + db * 32 + g * 8 + hi * 4] = v4;
    }
}

// ---------------------------------------------------------------------------
extern "C" void kernel_launch(void* const* d_in, const int* in_sizes, int n_in,
                              void* d_out, int out_size, void* d_ws, size_t ws_size,
                              hipStream_t stream)
{
  const float* x_q  = (const float*)d_in[0];
  const float* x_kv = (const float*)d_in[1];
  const void*  pad  = d_in[2];
  const float* wq = (const float*)d_in[3];
  const float* bq = (const float*)d_in[4];
  const float* wk = (const float*)d_in[5];
  const float* bk = (const float*)d_in[6];
  const float* wv = (const float*)d_in[7];
  const float* bv = (const float*)d_in[8];
  const float* wo = (const float*)d_in[9];
  const float* bo = (const float*)d_in[10];
  float* out = (float*)d_out;

  char* ws = (char*)d_ws;
  const size_t MB = (size_t)1 << 20;
  const size_t fullElems = (size_t)BB * NN * DD;  // 4M
  const size_t batchElems = (size_t)NN * DD;      // 2M

  if (ws_size >= 49 * MB) {
    bf16* Xqb   = (bf16*)(ws);            // 8 MB, reused as Op after Q-GEMM
    bf16* Xkvb  = (bf16*)(ws + 8 * MB);
    bf16* Wtq   = (bf16*)(ws + 16 * MB);
    bf16* Wtk   = (bf16*)(ws + 18 * MB);
    bf16* Wtv   = (bf16*)(ws + 20 * MB);
    bf16* Wto   = (bf16*)(ws + 22 * MB);
    bf16* Qp    = (bf16*)(ws + 24 * MB);
    bf16* Kp    = (bf16*)(ws + 32 * MB);
    bf16* VtG   = (bf16*)(ws + 40 * MB);
    float* biasF = (float*)(ws + 48 * MB);  // 16 KB
    bf16* Op    = Xqb;

    prep_kernel<<<5121, 256, 0, stream>>>(x_q, x_kv, Xqb, Xkvb, 4096, (int)fullElems,
                                          wq, wk, wv, wo, Wtq, Wtk, Wtv, Wto,
                                          (const unsigned*)pad, biasF);
    // sequential projection GEMMs: each launch's working set fits per-XCD L2;
    // K then V adjacent so V's Xkv A-panels are L2-hot.
    qkv_gemm32<<<256, 256, 0, stream>>>(Xqb, Xkvb, Wtq, Wtk, Wtv, bq, bk, bv, Qp, Kp, VtG, 8, 1);
    qkv_gemm32<<<256, 256, 0, stream>>>(Xqb, Xkvb, Wtq, Wtk, Wtv, bq, bk, bv, Qp, Kp, VtG, 8, 2);
    qkv_gemm32<<<256, 256, 0, stream>>>(Xqb, Xkvb, Wtq, Wtk, Wtv, bq, bk, bv, Qp, Kp, VtG, 8, 0);
    attn_kernel<<<512, 256, 0, stream>>>(Qp, Kp, VtG, biasF, Op, 5);
    out_gemm<<<512, 256, 0, stream>>>(Op, Wto, bo, out);
  } else {
    bf16* Wtq   = (bf16*)(ws);
    bf16* Wtk   = (bf16*)(ws + 2 * MB);
    bf16* Wtv   = (bf16*)(ws + 4 * MB);
    bf16* Wto   = (bf16*)(ws + 6 * MB);
    bf16* Xqb   = (bf16*)(ws + 8 * MB);   // 4 MB, reused as Op
    bf16* Xkvb  = (bf16*)(ws + 12 * MB);
    bf16* Qp    = (bf16*)(ws + 16 * MB);
    bf16* Kp    = (bf16*)(ws + 20 * MB);
    bf16* VtG   = (bf16*)(ws + 24 * MB);
    float* biasF = (float*)(ws + 28 * MB);
    bf16* Op    = Xqb;

    for (int b = 0; b < BB; b++) {
      if (b == 0)
        prep_kernel<<<3073, 256, 0, stream>>>(x_q, x_kv, Xqb, Xkvb, 2048, (int)batchElems,
                                              wq, wk, wv, wo, Wtq, Wtk, Wtv, Wto,
                                              (const unsigned*)pad, biasF);
      else
        prep_kernel<<<2048, 256, 0, stream>>>(x_q + b * batchElems, x_kv + b * batchElems,
                                              Xqb, Xkvb, 2048, (int)batchElems,
                                              wq, wk, wv, wo, Wtq, Wtk, Wtv, Wto,
                                              (const unsigned*)pad, biasF);
      qkv_gemm32<<<128, 256, 0, stream>>>(Xqb, Xkvb, Wtq, Wtk, Wtv, bq, bk, bv, Qp, Kp, VtG, 7, 1);
      qkv_gemm32<<<128, 256, 0, stream>>>(Xqb, Xkvb, Wtq, Wtk, Wtv, bq, bk, bv, Qp, Kp, VtG, 7, 2);
      qkv_gemm32<<<128, 256, 0, stream>>>(Xqb, Xkvb, Wtq, Wtk, Wtv, bq, bk, bv, Qp, Kp, VtG, 7, 0);
      attn_kernel<<<256, 256, 0, stream>>>(Qp, Kp, VtG, biasF + b * LL, Op, 4);
      out_gemm<<<256, 256, 0, stream>>>(Op, Wto, bo, out + b * batchElems);
    }
  }
}

// Round 9
// 231.863 us; speedup vs baseline: 1.0632x; 1.0632x over previous
//
#include <hip/hip_runtime.h>
#include <hip/hip_bf16.h>
#include <math.h>

typedef __bf16 bf16;
typedef __attribute__((ext_vector_type(8))) __bf16 bf16x8;
typedef __attribute__((ext_vector_type(4))) __bf16 bf16x4;
typedef __attribute__((ext_vector_type(4))) float floatx4;
typedef __attribute__((ext_vector_type(16))) float floatx16;

#define BB 2
#define NN 2048
#define LL 2048
#define DD 1024
#define HH 16
#define HDD 64

// Q pre-scale: HD^-0.5 * log2(e) -> scores in log2 units
#define QSCALE (0.125f * 1.44269504f)
#define PCLAMP 21.66f
#define MBIAS  (-100000.0f)

// async global->LDS, 16B per lane. LDS dest must be wave-uniform + lane*16.
__device__ __forceinline__ void async16(const bf16* g, bf16* l) {
  __builtin_amdgcn_global_load_lds((const __attribute__((address_space(1))) void*)(g),
                                   (__attribute__((address_space(3))) void*)(l), 16, 0, 0);
}

// v_cvt_pk_bf16_f32: pack two f32 -> u32 of {lo=bf16(a), hi=bf16(b)}
__device__ __forceinline__ unsigned cvtpk(float a, float b) {
  unsigned r;
  asm("v_cvt_pk_bf16_f32 %0, %1, %2" : "=v"(r) : "v"(a), "v"(b));
  return r;
}

// permlane32_swap: x'[0:31]=x[0:31], x'[32+j]=y[j]; y'[j]=x[32+j], y'[32:63]=y[32:63]
__device__ __forceinline__ void plswap(unsigned &x, unsigned &y) {
  auto r = __builtin_amdgcn_permlane32_swap(x, y, false, false);
  x = (unsigned)r[0];
  y = (unsigned)r[1];
}

__device__ __forceinline__ bf16x8 mk_frag(unsigned w0, unsigned w1, unsigned w2, unsigned w3) {
  union { unsigned u[4]; bf16x8 b; } f;
  f.u[0] = w0; f.u[1] = w1; f.u[2] = w2; f.u[3] = w3;
  return f.b;
}

// ---------------------------------------------------------------------------
// Fused prep: [0,nconv) f32->bf16 converts (two inputs, nconv/2 blocks each),
// [nconv, nconv+1024) W-transpose tiles (4 matrices), [nconv+1024] mask ->
// biasF floats (dtype auto-detect: int32 {0,1} / bytes / f32 {0,1}).
// ---------------------------------------------------------------------------
__global__ __launch_bounds__(256) void prep_kernel(
    const float* __restrict__ xq, const float* __restrict__ xkv,
    bf16* __restrict__ Xqb, bf16* __restrict__ Xkvb, int nconv, int elemsEach,
    const float* __restrict__ W0, const float* __restrict__ W1,
    const float* __restrict__ W2, const float* __restrict__ W3,
    bf16* __restrict__ T0, bf16* __restrict__ T1,
    bf16* __restrict__ T2, bf16* __restrict__ T3,
    const unsigned* __restrict__ mask, float* __restrict__ biasF)
{
  __shared__ bf16 Tb[64][72];
  const int bid = blockIdx.x;
  const int t = threadIdx.x;

  if (bid < nconv) {
    const int half = nconv >> 1;
    const float* s = (bid < half) ? xq : xkv;
    bf16* d = (bid < half) ? Xqb : Xkvb;
    int gid = (bid < half) ? bid : bid - half;
    int idx = (gid * 256 + t) * 8;
    if (idx >= elemsEach) return;
    floatx4 a = *(const floatx4*)&s[idx];
    floatx4 b = *(const floatx4*)&s[idx + 4];
    bf16x8 o;
#pragma unroll
    for (int e = 0; e < 4; e++) { o[e] = (bf16)a[e]; o[4 + e] = (bf16)b[e]; }
    *(bf16x8*)&d[idx] = o;
    return;
  }
  if (bid < nconv + 1024) {
    const int wb = bid - nconv;
    const int which = wb >> 8;
    const float* W = which == 0 ? W0 : which == 1 ? W1 : which == 2 ? W2 : W3;
    bf16*       T = which == 0 ? T0 : which == 1 ? T1 : which == 2 ? T2 : T3;
    const int tile = wb & 255;
    const int k0 = (tile >> 4) * 64, n0 = (tile & 15) * 64;
    const int r = t >> 2;
    const int c = (t & 3) * 16;
    const float* Wr = W + (size_t)(k0 + r) * 1024 + n0 + c;
    floatx4 f0 = *(const floatx4*)(Wr + 0);
    floatx4 f1 = *(const floatx4*)(Wr + 4);
    floatx4 f2 = *(const floatx4*)(Wr + 8);
    floatx4 f3 = *(const floatx4*)(Wr + 12);
#pragma unroll
    for (int e = 0; e < 4; e++) {
      Tb[c + e][r]      = (bf16)f0[e];
      Tb[c + 4 + e][r]  = (bf16)f1[e];
      Tb[c + 8 + e][r]  = (bf16)f2[e];
      Tb[c + 12 + e][r] = (bf16)f3[e];
    }
    __syncthreads();
    bf16* Tr = T + (size_t)(n0 + r) * 1024 + k0 + c;
    *(bf16x8*)&Tr[0] = *(const bf16x8*)&Tb[r][c];
    *(bf16x8*)&Tr[8] = *(const bf16x8*)&Tb[r][c + 8];
    return;
  }
  // mask -> biasF (one block)
  __shared__ int hasBig, hasFloat;
  if (t == 0) { hasBig = 0; hasFloat = 0; }
  __syncthreads();
  int big = 0, flt = 0;
  for (int idx = t; idx < 1024; idx += 256) {
    unsigned v = mask[idx];
    if (v == 0x3F800000u) flt = 1;
    else if (v > 1u) big = 1;
  }
  if (big) atomicOr(&hasBig, 1);
  if (flt) atomicOr(&hasFloat, 1);
  __syncthreads();
  const int mode = hasFloat ? 2 : (hasBig ? 1 : 0);
  for (int k = t * 16; k < t * 16 + 16; k++) {
    bool m;
    if (mode == 0)      m = ((const int*)mask)[k] != 0;
    else if (mode == 1) m = ((const unsigned char*)mask)[k] != 0;
    else                m = ((const float*)mask)[k] != 0.0f;
    biasF[k] = m ? MBIAS : 0.0f;
  }
}

// ---------------------------------------------------------------------------
// qkv GEMM body: 128x128 tile, BK=32, 32x32x16 MFMAs; 4-slot LDS rotation,
// 2-ahead counted-vmcnt pipeline, stage issued AFTER the barrier.
// FUSED 3-GEMM launch (round-7's sequential split regressed +29 us: at
// 1 block/CU the pipeline couldn't hide L2 latency).
// ---------------------------------------------------------------------------
template <typename TC>
__device__ __forceinline__ void gemm_body32(
    int bx, const bf16* __restrict__ A, const bf16* __restrict__ Wt,
    const float* __restrict__ bias, TC* __restrict__ C, float scale, int transv)
{
  __shared__ bf16 As[4][128 * 32];
  __shared__ bf16 Bs[4][128 * 32];

  const int tm = bx >> 3, tn = bx & 7;
  const int m0 = tm * 128, n0 = tn * 128;
  const int t = threadIdx.x;
  const int w = t >> 6, l = t & 63;
  const int col = l & 31, half = l >> 5;
  const int wm = (w >> 1) * 64, wn = (w & 1) * 64;
  const int sr  = t >> 2;                          // dest row 0..63
  const int scl = (t & 3) * 8;                     // linear LDS chunk (elems)
  const int scs = (((t & 3) ^ ((t >> 3) & 3)) * 8); // swizzled global chunk
  const int csw = (col >> 1) & 3;                  // frag de-swizzle key

  floatx16 acc[2][2];
#pragma unroll
  for (int mi = 0; mi < 2; mi++)
#pragma unroll
    for (int ni = 0; ni < 2; ni++)
#pragma unroll
      for (int e = 0; e < 16; e++) acc[mi][ni][e] = 0.0f;

  auto STAGE = [&](int k0, int s) {
    async16(&A[(size_t)(m0 + sr) * 1024 + k0 + scs],       &As[s][sr * 32 + scl]);
    async16(&A[(size_t)(m0 + 64 + sr) * 1024 + k0 + scs],  &As[s][(64 + sr) * 32 + scl]);
    async16(&Wt[(size_t)(n0 + sr) * 1024 + k0 + scs],      &Bs[s][sr * 32 + scl]);
    async16(&Wt[(size_t)(n0 + 64 + sr) * 1024 + k0 + scs], &Bs[s][(64 + sr) * 32 + scl]);
  };

  STAGE(0, 0);
  STAGE(32, 1);
  STAGE(64, 2);
  const int NK = 1024 / 32;  // 32
  for (int k = 0; k < NK; k++) {
    // allow the 2 newest stages to stay in flight; drain stage(k)
    if (k + 2 <= NK - 1)      asm volatile("s_waitcnt vmcnt(8)" ::: "memory");
    else if (k + 1 <= NK - 1) asm volatile("s_waitcnt vmcnt(4)" ::: "memory");
    else                      asm volatile("s_waitcnt vmcnt(0)" ::: "memory");
    __builtin_amdgcn_s_barrier();
    __builtin_amdgcn_sched_barrier(0);
    if (k + 3 < NK) STAGE((k + 3) * 32, (k + 3) & 3);  // post-barrier: slot free
    const bf16* as = &As[k & 3][0];
    const bf16* bs = &Bs[k & 3][0];
#pragma unroll
    for (int kk = 0; kk < 2; kk++) {
      const int ch = ((kk * 2 + half) ^ csw) * 8;  // de-swizzled chunk offset
      bf16x8 af[2], bfr[2];
#pragma unroll
      for (int mi = 0; mi < 2; mi++)
        af[mi] = *(const bf16x8*)&as[(wm + mi * 32 + col) * 32 + ch];
#pragma unroll
      for (int ni = 0; ni < 2; ni++)
        bfr[ni] = *(const bf16x8*)&bs[(wn + ni * 32 + col) * 32 + ch];
#pragma unroll
      for (int mi = 0; mi < 2; mi++)
#pragma unroll
        for (int ni = 0; ni < 2; ni++)
          acc[mi][ni] = __builtin_amdgcn_mfma_f32_32x32x16_bf16(af[mi], bfr[ni], acc[mi][ni], 0, 0, 0);
    }
  }
  // 32x32 C/D layout: col = lane&31, row = (reg&3) + 8*(reg>>2) + 4*(lane>>5)
#pragma unroll
  for (int ni = 0; ni < 2; ni++) {
    int colg = n0 + wn + ni * 32 + col;
    float bv = bias[colg];
#pragma unroll
    for (int mi = 0; mi < 2; mi++) {
      int rbase = m0 + wm + mi * 32 + half * 4;
      if (transv) {
#pragma unroll
        for (int g = 0; g < 4; g++) {
          int key0 = rbase + g * 8;
          int bb = key0 >> 11, key = key0 & 2047;
          bf16x4 v4;
#pragma unroll
          for (int r = 0; r < 4; r++) v4[r] = (bf16)(acc[mi][ni][g * 4 + r] + bv);
          *(bf16x4*)&((bf16*)C)[(size_t)bb * (DD * (size_t)LL) + (size_t)colg * LL + key] = v4;
        }
      } else {
#pragma unroll
        for (int g = 0; g < 4; g++)
#pragma unroll
          for (int r = 0; r < 4; r++)
            C[(size_t)(rbase + g * 8 + r) * 1024 + colg] = (TC)((acc[mi][ni][g * 4 + r] + bv) * scale);
      }
    }
  }
}

// Fused Q/K/V projection: grid = 3 << shift; which = bid >> shift.
// XCD-bijective swizzle within each GEMM's block range.
__global__ __launch_bounds__(256) void qkv_gemm32(
    const bf16* __restrict__ Xq, const bf16* __restrict__ Xkv,
    const bf16* __restrict__ Wtq, const bf16* __restrict__ Wtk, const bf16* __restrict__ Wtv,
    const float* __restrict__ bq, const float* __restrict__ bk, const float* __restrict__ bv,
    bf16* __restrict__ Qp, bf16* __restrict__ Kp, bf16* __restrict__ VtG, int shift)
{
  const int bid = blockIdx.x;
  const int which = bid >> shift;
  const int bx0 = bid & ((1 << shift) - 1);
  const int q = (1 << shift) >> 3;
  const int bx = (bx0 & 7) * q + (bx0 >> 3);   // XCD-contiguous tm ranges
  if (which == 0)      gemm_body32<bf16>(bx, Xq,  Wtq, bq, Qp,  QSCALE, 0);
  else if (which == 1) gemm_body32<bf16>(bx, Xkv, Wtk, bk, Kp,  1.0f,   0);
  else                 gemm_body32<bf16>(bx, Xkv, Wtv, bv, VtG, 1.0f,   1);
}

// ---------------------------------------------------------------------------
// out GEMM: 128x64 tile, BK=32, 16x16x32 MFMAs; 4-slot 2-ahead pipeline,
// stage issued post-barrier.
// ---------------------------------------------------------------------------
__global__ __launch_bounds__(256) void out_gemm(
    const bf16* __restrict__ A, const bf16* __restrict__ Wt,
    const float* __restrict__ bias, float* __restrict__ C)
{
  __shared__ bf16 As[4][128 * 32];
  __shared__ bf16 Bs[4][64 * 32];

  const int bid = blockIdx.x;
  const int qs = gridDim.x >> 3;
  const int bx = (bid & 7) * qs + (bid >> 3);  // XCD-bijective swizzle
  const int tm = bx >> 4, tn = bx & 15;
  const int m0 = tm * 128, n0 = tn * 64;
  const int t = threadIdx.x;
  const int w = t >> 6, l = t & 63;
  const int q = l >> 4, i = l & 15;
  const int wm = (w >> 1) * 64, wn = (w & 1) * 32;
  const int sr  = t >> 2;
  const int scl = (t & 3) * 8;
  const int scs = (((t & 3) ^ ((t >> 3) & 3)) * 8);
  const int isw = (i >> 1) & 3;

  const floatx4 zero = {0.f, 0.f, 0.f, 0.f};
  floatx4 acc[4][2];
#pragma unroll
  for (int mi = 0; mi < 4; mi++)
#pragma unroll
    for (int ni = 0; ni < 2; ni++) acc[mi][ni] = zero;

  auto STAGE = [&](int k0, int s) {
    async16(&A[(size_t)(m0 + sr) * 1024 + k0 + scs],       &As[s][sr * 32 + scl]);
    async16(&A[(size_t)(m0 + 64 + sr) * 1024 + k0 + scs],  &As[s][(64 + sr) * 32 + scl]);
    async16(&Wt[(size_t)(n0 + sr) * 1024 + k0 + scs],      &Bs[s][sr * 32 + scl]);
  };

  STAGE(0, 0);
  STAGE(32, 1);
  STAGE(64, 2);
  const int NK = 1024 / 32;
  for (int k = 0; k < NK; k++) {
    if (k + 2 <= NK - 1)      asm volatile("s_waitcnt vmcnt(6)" ::: "memory");
    else if (k + 1 <= NK - 1) asm volatile("s_waitcnt vmcnt(3)" ::: "memory");
    else                      asm volatile("s_waitcnt vmcnt(0)" ::: "memory");
    __builtin_amdgcn_s_barrier();
    __builtin_amdgcn_sched_barrier(0);
    if (k + 3 < NK) STAGE((k + 3) * 32, (k + 3) & 3);
    const bf16* as = &As[k & 3][0];
    const bf16* bs = &Bs[k & 3][0];
    const int ch = (q ^ isw) * 8;
    bf16x8 af[4], bfr[2];
#pragma unroll
    for (int mi = 0; mi < 4; mi++)
      af[mi] = *(const bf16x8*)&as[(wm + mi * 16 + i) * 32 + ch];
#pragma unroll
    for (int ni = 0; ni < 2; ni++)
      bfr[ni] = *(const bf16x8*)&bs[(wn + ni * 16 + i) * 32 + ch];
#pragma unroll
    for (int mi = 0; mi < 4; mi++)
#pragma unroll
      for (int ni = 0; ni < 2; ni++)
        acc[mi][ni] = __builtin_amdgcn_mfma_f32_16x16x32_bf16(af[mi], bfr[ni], acc[mi][ni], 0, 0, 0);
  }
#pragma unroll
  for (int ni = 0; ni < 2; ni++) {
    int colg = n0 + wn + ni * 16 + i;
    float bv = bias[colg];
#pragma unroll
    for (int mi = 0; mi < 4; mi++) {
      int row = m0 + wm + mi * 16 + q * 4;
#pragma unroll
      for (int r = 0; r < 4; r++)
        C[(size_t)(row + r) * 1024 + colg] = acc[mi][ni][r] + bv;
    }
  }
}

// ---------------------------------------------------------------------------
// Flash attention v6: 512-thread blocks, 8 waves x 32 qrows = 256 qrows per
// block, grid 256 (= 2 blocks/CU, ALL blocks resident, zero tail). This
// doubles occupancy to 4 waves/SIMD (was 2): the v5 analysis showed issue
// work per iteration ~600 cyc/wave vs a 4640-cyc period -> latency-bound,
// not pipe-bound. One K/V staging now serves 8 waves (STAGE = 2 ops/thread).
// Per-wave structure unchanged (proven): cross-tile QK(t)/PV(t-1)/softmax(t)
// pipeline, counted vmcnt (never 0 in-loop), in-register P transpose
// (cvt_pk + permlane32_swap), 32x32x16 MFMAs, fixed-max softmax in log2
// units, XOR-chunk-swizzled K/V staging, 4-slot LDS rotation (64 KB).
// ---------------------------------------------------------------------------
__global__ __launch_bounds__(512) void attn_kernel(
    const bf16* __restrict__ Q, const bf16* __restrict__ K,
    const bf16* __restrict__ Vt, const float* __restrict__ biasF,
    bf16* __restrict__ O, int hbits)
{
  __shared__ bf16 Kbuf[4][64 * 64];
  __shared__ bf16 Vbuf[4][64 * 64];

  const int bid = blockIdx.x;
  const int qt = bid >> hbits;
  const int hb = bid & ((1 << hbits) - 1);
  const int h  = (hbits == 5) ? (hb >> 1) : hb;
  const int b  = (hbits == 5) ? (hb & 1) : 0;
  const int t = threadIdx.x;
  const int w = t >> 6, lane = t & 63;   // w = 0..7
  const int col = lane & 31;     // qrow within wave / MFMA col
  const int hi  = lane >> 5;
  const int lsw = lane & 7;      // fragment de-swizzle key

  const bf16* Qb = Q  + (size_t)b * (NN * DD) + h * HDD;
  const bf16* Kb = K  + (size_t)b * (LL * DD) + h * HDD;
  const bf16* Vb = Vt + (size_t)b * (DD * (size_t)LL) + (size_t)(h * HDD) * LL;
  const float* biasFb = biasF + b * LL;

  const int qrow = qt * 256 + w * 32;

  // Q fragment: B[col=qrow][k=d], k = dc*16 + hi*8 + e
  bf16x8 qfrag[4];
#pragma unroll
  for (int dc = 0; dc < 4; dc++)
    qfrag[dc] = *(const bf16x8*)&Qb[(size_t)(qrow + col) * DD + dc * 16 + hi * 8];

  floatx16 oacc[2];
#pragma unroll
  for (int db = 0; db < 2; db++)
#pragma unroll
    for (int e = 0; e < 16; e++) oacc[db][e] = 0.0f;
  float psum = 0.0f;

  // staging indices: 512 threads cover a full 64x64 bf16 tile in ONE round
  const int sr  = t >> 3;                       // dest row 0..63
  const int scl = (t & 7) * 8;                  // linear LDS chunk (elems)
  const int scs = ((t & 7) ^ (sr & 7)) * 8;     // swizzled global chunk (elems)

  auto STAGE = [&](int tile, int slot) {
    const int k0 = tile * 64;
    async16(&Kb[(size_t)(k0 + sr) * DD + scs], &Kbuf[slot][sr * 64 + scl]);
    async16(&Vb[(size_t)sr * LL + k0 + scs],   &Vbuf[slot][sr * 64 + scl]);
  };

  floatx4 pb[2][4];      // bias for the CURRENT tile (C-init of QK)
  bf16x8 pfp[4];         // P fragments of the PREVIOUS tile (PV input)
  floatx16 sacc[2];

  auto QK = [&](int slot) {
#pragma unroll
    for (int kb = 0; kb < 2; kb++)
#pragma unroll
      for (int g = 0; g < 4; g++)
#pragma unroll
        for (int rr = 0; rr < 4; rr++)
          sacc[kb][g * 4 + rr] = pb[kb][g][rr];
    __builtin_amdgcn_s_setprio(1);
#pragma unroll
    for (int kb = 0; kb < 2; kb++)
#pragma unroll
      for (int dc = 0; dc < 4; dc++) {
        bf16x8 kf = *(const bf16x8*)&Kbuf[slot][(kb * 32 + col) * 64 + ((dc * 2 + hi) ^ lsw) * 8];
        sacc[kb] = __builtin_amdgcn_mfma_f32_32x32x16_bf16(kf, qfrag[dc], sacc[kb], 0, 0, 0);
      }
  };

  auto PV = [&](int slot) {
#pragma unroll
    for (int db = 0; db < 2; db++)
#pragma unroll
      for (int kc = 0; kc < 4; kc++) {
        bf16x8 vf = *(const bf16x8*)&Vbuf[slot][(db * 32 + col) * 64 + ((kc * 2 + hi) ^ lsw) * 8];
        oacc[db] = __builtin_amdgcn_mfma_f32_32x32x16_bf16(vf, pfp[kc], oacc[db], 0, 0, 0);
      }
    __builtin_amdgcn_s_setprio(0);
  };

  // softmax on sacc -> pfp (P fragments for next iter's PV); prefetch bias
  auto SOFTMAX = [&](int nextTile) {
#pragma unroll
    for (int kb = 0; kb < 2; kb++)
#pragma unroll
      for (int hh = 0; hh < 2; hh++) {
        float pv[8];
#pragma unroll
        for (int e = 0; e < 8; e++) {
          float p = __builtin_amdgcn_exp2f(fminf(sacc[kb][hh * 8 + e], PCLAMP));
          psum += p;
          pv[e] = p;
        }
        unsigned a0 = cvtpk(pv[0], pv[1]);
        unsigned a1 = cvtpk(pv[2], pv[3]);
        unsigned b0 = cvtpk(pv[4], pv[5]);
        unsigned b1 = cvtpk(pv[6], pv[7]);
        plswap(a0, b0);
        plswap(a1, b1);
        pfp[kb * 2 + hh] = mk_frag(a0, a1, b0, b1);
      }
    const int kn = (nextTile & 31) * 64;
#pragma unroll
    for (int kb = 0; kb < 2; kb++)
#pragma unroll
      for (int g = 0; g < 4; g++)
        pb[kb][g] = *(const floatx4*)&biasFb[kn + kb * 32 + g * 8 + hi * 4];
  };

  // prologue: tile-0 bias first (oldest vmem), then stage tiles 0,1
#pragma unroll
  for (int kb = 0; kb < 2; kb++)
#pragma unroll
    for (int g = 0; g < 4; g++)
      pb[kb][g] = *(const floatx4*)&biasFb[kb * 32 + g * 8 + hi * 4];
  STAGE(0, 0);
  STAGE(1, 1);

  // counted-vmcnt barrier: stage(0)'s 2 loads landed; stage(1) in flight
  asm volatile("s_waitcnt vmcnt(2)" ::: "memory");
  __builtin_amdgcn_s_barrier();
  __builtin_amdgcn_sched_barrier(0);

  // iteration 0 (peeled: no PV yet)
  QK(0);
  __builtin_amdgcn_s_setprio(0);
  SOFTMAX(1);

  const int NT = LL / 64;  // 32
  for (int kt = 1; kt < NT; kt++) {
    if (kt + 1 < NT) {
      STAGE(kt + 1, (kt + 1) & 3);
      // drain stage(kt) and older (incl. bias loads); stage(kt+1) in flight
      asm volatile("s_waitcnt vmcnt(2)" ::: "memory");
    } else {
      asm volatile("s_waitcnt vmcnt(0)" ::: "memory");
    }
    __builtin_amdgcn_s_barrier();
    __builtin_amdgcn_sched_barrier(0);
    QK(kt & 3);          // sacc for tile kt (prio 1 from inside QK)
    PV((kt - 1) & 3);    // consumes pfp (tile kt-1); prio back to 0 after
    SOFTMAX(kt + 1);     // pfp <- tile kt; prefetch bias kt+1
  }
  // epilogue: PV for the last tile
  __builtin_amdgcn_s_setprio(1);
  PV((NT - 1) & 3);

  // lanes l and l+32 share qrow and jointly hold all keys
  psum += __shfl_xor(psum, 32, 64);
  float inv = 1.0f / fmaxf(psum, 1e-30f);

  bf16* Ob = O + (size_t)b * (NN * DD) + h * HDD;
#pragma unroll
  for (int db = 0; db < 2; db++)
#pragma unroll
    for (int g = 0; g < 4; g++) {
      bf16x4 v4;
#pragma unroll
      for (int rr = 0; rr < 4; rr++) v4[rr] = (bf16)(oacc[db][g * 4 + rr] * inv);
      *(bf16x4*)&Ob[(size_t)(qrow + col) * DD + db * 32 + g * 8 + hi * 4] = v4;
    }
}

// ---------------------------------------------------------------------------
extern "C" void kernel_launch(void* const* d_in, const int* in_sizes, int n_in,
                              void* d_out, int out_size, void* d_ws, size_t ws_size,
                              hipStream_t stream)
{
  const float* x_q  = (const float*)d_in[0];
  const float* x_kv = (const float*)d_in[1];
  const void*  pad  = d_in[2];
  const float* wq = (const float*)d_in[3];
  const float* bq = (const float*)d_in[4];
  const float* wk = (const float*)d_in[5];
  const float* bk = (const float*)d_in[6];
  const float* wv = (const float*)d_in[7];
  const float* bv = (const float*)d_in[8];
  const float* wo = (const float*)d_in[9];
  const float* bo = (const float*)d_in[10];
  float* out = (float*)d_out;

  char* ws = (char*)d_ws;
  const size_t MB = (size_t)1 << 20;
  const size_t fullElems = (size_t)BB * NN * DD;  // 4M
  const size_t batchElems = (size_t)NN * DD;      // 2M

  if (ws_size >= 49 * MB) {
    bf16* Xqb   = (bf16*)(ws);            // 8 MB, reused as Op after Q-GEMM
    bf16* Xkvb  = (bf16*)(ws + 8 * MB);
    bf16* Wtq   = (bf16*)(ws + 16 * MB);
    bf16* Wtk   = (bf16*)(ws + 18 * MB);
    bf16* Wtv   = (bf16*)(ws + 20 * MB);
    bf16* Wto   = (bf16*)(ws + 22 * MB);
    bf16* Qp    = (bf16*)(ws + 24 * MB);
    bf16* Kp    = (bf16*)(ws + 32 * MB);
    bf16* VtG   = (bf16*)(ws + 40 * MB);
    float* biasF = (float*)(ws + 48 * MB);  // 16 KB
    bf16* Op    = Xqb;

    prep_kernel<<<5121, 256, 0, stream>>>(x_q, x_kv, Xqb, Xkvb, 4096, (int)fullElems,
                                          wq, wk, wv, wo, Wtq, Wtk, Wtv, Wto,
                                          (const unsigned*)pad, biasF);
    qkv_gemm32<<<768, 256, 0, stream>>>(Xqb, Xkvb, Wtq, Wtk, Wtv, bq, bk, bv, Qp, Kp, VtG, 8);
    attn_kernel<<<256, 512, 0, stream>>>(Qp, Kp, VtG, biasF, Op, 5);
    out_gemm<<<512, 256, 0, stream>>>(Op, Wto, bo, out);
  } else {
    bf16* Wtq   = (bf16*)(ws);
    bf16* Wtk   = (bf16*)(ws + 2 * MB);
    bf16* Wtv   = (bf16*)(ws + 4 * MB);
    bf16* Wto   = (bf16*)(ws + 6 * MB);
    bf16* Xqb   = (bf16*)(ws + 8 * MB);   // 4 MB, reused as Op
    bf16* Xkvb  = (bf16*)(ws + 12 * MB);
    bf16* Qp    = (bf16*)(ws + 16 * MB);
    bf16* Kp    = (bf16*)(ws + 20 * MB);
    bf16* VtG   = (bf16*)(ws + 24 * MB);
    float* biasF = (float*)(ws + 28 * MB);
    bf16* Op    = Xqb;

    for (int b = 0; b < BB; b++) {
      if (b == 0)
        prep_kernel<<<3073, 256, 0, stream>>>(x_q, x_kv, Xqb, Xkvb, 2048, (int)batchElems,
                                              wq, wk, wv, wo, Wtq, Wtk, Wtv, Wto,
                                              (const unsigned*)pad, biasF);
      else
        prep_kernel<<<2048, 256, 0, stream>>>(x_q + b * batchElems, x_kv + b * batchElems,
                                              Xqb, Xkvb, 2048, (int)batchElems,
                                              wq, wk, wv, wo, Wtq, Wtk, Wtv, Wto,
                                              (const unsigned*)pad, biasF);
      qkv_gemm32<<<384, 256, 0, stream>>>(Xqb, Xkvb, Wtq, Wtk, Wtv, bq, bk, bv, Qp, Kp, VtG, 7);
      attn_kernel<<<128, 512, 0, stream>>>(Qp, Kp, VtG, biasF + b * LL, Op, 4);
      out_gemm<<<256, 256, 0, stream>>>(Op, Wto, bo, out + b * batchElems);
    }
  }
}

// Round 10
// 208.267 us; speedup vs baseline: 1.1836x; 1.1133x over previous
//
#include <hip/hip_runtime.h>
#include <hip/hip_bf16.h>
#include <math.h>

typedef __bf16 bf16;
typedef __attribute__((ext_vector_type(8))) __bf16 bf16x8;
typedef __attribute__((ext_vector_type(4))) __bf16 bf16x4;
typedef __attribute__((ext_vector_type(4))) float floatx4;
typedef __attribute__((ext_vector_type(16))) float floatx16;

#define BB 2
#define NN 2048
#define LL 2048
#define DD 1024
#define HH 16
#define HDD 64

// Q pre-scale: HD^-0.5 * log2(e) -> scores in log2 units
#define QSCALE (0.125f * 1.44269504f)
#define PCLAMP 21.66f
#define MBIAS  (-100000.0f)

// async global->LDS, 16B per lane. LDS dest must be wave-uniform + lane*16.
__device__ __forceinline__ void async16(const bf16* g, bf16* l) {
  __builtin_amdgcn_global_load_lds((const __attribute__((address_space(1))) void*)(g),
                                   (__attribute__((address_space(3))) void*)(l), 16, 0, 0);
}

// v_cvt_pk_bf16_f32: pack two f32 -> u32 of {lo=bf16(a), hi=bf16(b)}
__device__ __forceinline__ unsigned cvtpk(float a, float b) {
  unsigned r;
  asm("v_cvt_pk_bf16_f32 %0, %1, %2" : "=v"(r) : "v"(a), "v"(b));
  return r;
}

// permlane32_swap: x'[0:31]=x[0:31], x'[32+j]=y[j]; y'[j]=x[32+j], y'[32:63]=y[32:63]
__device__ __forceinline__ void plswap(unsigned &x, unsigned &y) {
  auto r = __builtin_amdgcn_permlane32_swap(x, y, false, false);
  x = (unsigned)r[0];
  y = (unsigned)r[1];
}

__device__ __forceinline__ bf16x8 mk_frag(unsigned w0, unsigned w1, unsigned w2, unsigned w3) {
  union { unsigned u[4]; bf16x8 b; } f;
  f.u[0] = w0; f.u[1] = w1; f.u[2] = w2; f.u[3] = w3;
  return f.b;
}

// ---------------------------------------------------------------------------
// Fused prep: [0,nconv) f32->bf16 converts (two inputs, nconv/2 blocks each),
// [nconv, nconv+1024) W-transpose tiles (4 matrices), [nconv+1024] mask ->
// biasF floats (dtype auto-detect: int32 {0,1} / bytes / f32 {0,1}).
// ---------------------------------------------------------------------------
__global__ __launch_bounds__(256) void prep_kernel(
    const float* __restrict__ xq, const float* __restrict__ xkv,
    bf16* __restrict__ Xqb, bf16* __restrict__ Xkvb, int nconv, int elemsEach,
    const float* __restrict__ W0, const float* __restrict__ W1,
    const float* __restrict__ W2, const float* __restrict__ W3,
    bf16* __restrict__ T0, bf16* __restrict__ T1,
    bf16* __restrict__ T2, bf16* __restrict__ T3,
    const unsigned* __restrict__ mask, float* __restrict__ biasF)
{
  __shared__ bf16 Tb[64][72];
  const int bid = blockIdx.x;
  const int t = threadIdx.x;

  if (bid < nconv) {
    const int half = nconv >> 1;
    const float* s = (bid < half) ? xq : xkv;
    bf16* d = (bid < half) ? Xqb : Xkvb;
    int gid = (bid < half) ? bid : bid - half;
    int idx = (gid * 256 + t) * 8;
    if (idx >= elemsEach) return;
    floatx4 a = *(const floatx4*)&s[idx];
    floatx4 b = *(const floatx4*)&s[idx + 4];
    bf16x8 o;
#pragma unroll
    for (int e = 0; e < 4; e++) { o[e] = (bf16)a[e]; o[4 + e] = (bf16)b[e]; }
    *(bf16x8*)&d[idx] = o;
    return;
  }
  if (bid < nconv + 1024) {
    const int wb = bid - nconv;
    const int which = wb >> 8;
    const float* W = which == 0 ? W0 : which == 1 ? W1 : which == 2 ? W2 : W3;
    bf16*       T = which == 0 ? T0 : which == 1 ? T1 : which == 2 ? T2 : T3;
    const int tile = wb & 255;
    const int k0 = (tile >> 4) * 64, n0 = (tile & 15) * 64;
    const int r = t >> 2;
    const int c = (t & 3) * 16;
    const float* Wr = W + (size_t)(k0 + r) * 1024 + n0 + c;
    floatx4 f0 = *(const floatx4*)(Wr + 0);
    floatx4 f1 = *(const floatx4*)(Wr + 4);
    floatx4 f2 = *(const floatx4*)(Wr + 8);
    floatx4 f3 = *(const floatx4*)(Wr + 12);
#pragma unroll
    for (int e = 0; e < 4; e++) {
      Tb[c + e][r]      = (bf16)f0[e];
      Tb[c + 4 + e][r]  = (bf16)f1[e];
      Tb[c + 8 + e][r]  = (bf16)f2[e];
      Tb[c + 12 + e][r] = (bf16)f3[e];
    }
    __syncthreads();
    bf16* Tr = T + (size_t)(n0 + r) * 1024 + k0 + c;
    *(bf16x8*)&Tr[0] = *(const bf16x8*)&Tb[r][c];
    *(bf16x8*)&Tr[8] = *(const bf16x8*)&Tb[r][c + 8];
    return;
  }
  // mask -> biasF (one block)
  __shared__ int hasBig, hasFloat;
  if (t == 0) { hasBig = 0; hasFloat = 0; }
  __syncthreads();
  int big = 0, flt = 0;
  for (int idx = t; idx < 1024; idx += 256) {
    unsigned v = mask[idx];
    if (v == 0x3F800000u) flt = 1;
    else if (v > 1u) big = 1;
  }
  if (big) atomicOr(&hasBig, 1);
  if (flt) atomicOr(&hasFloat, 1);
  __syncthreads();
  const int mode = hasFloat ? 2 : (hasBig ? 1 : 0);
  for (int k = t * 16; k < t * 16 + 16; k++) {
    bool m;
    if (mode == 0)      m = ((const int*)mask)[k] != 0;
    else if (mode == 1) m = ((const unsigned char*)mask)[k] != 0;
    else                m = ((const float*)mask)[k] != 0.0f;
    biasF[k] = m ? MBIAS : 0.0f;
  }
}

// ---------------------------------------------------------------------------
// qkv GEMM body (round-6 proven, 48 KB -> 3 blocks/CU): 128x128 tile, BK=32,
// 32x32x16 MFMAs, 3-slot LDS rotation, stage-1-ahead + counted vmcnt + ONE
// barrier per K-step. (r7-r9's 4-slot/64KB variant cost 1 block/CU -> +14us;
// reverted.)
// ---------------------------------------------------------------------------
template <typename TC>
__device__ __forceinline__ void gemm_body32(
    int bx, const bf16* __restrict__ A, const bf16* __restrict__ Wt,
    const float* __restrict__ bias, TC* __restrict__ C, float scale, int transv)
{
  __shared__ bf16 As[3][128 * 32];
  __shared__ bf16 Bs[3][128 * 32];

  const int tm = bx >> 3, tn = bx & 7;
  const int m0 = tm * 128, n0 = tn * 128;
  const int t = threadIdx.x;
  const int w = t >> 6, l = t & 63;
  const int col = l & 31, half = l >> 5;
  const int wm = (w >> 1) * 64, wn = (w & 1) * 64;
  const int sr  = t >> 2;                          // dest row 0..63
  const int scl = (t & 3) * 8;                     // linear LDS chunk (elems)
  const int scs = (((t & 3) ^ ((t >> 3) & 3)) * 8); // swizzled global chunk
  const int csw = (col >> 1) & 3;                  // frag de-swizzle key

  floatx16 acc[2][2];
#pragma unroll
  for (int mi = 0; mi < 2; mi++)
#pragma unroll
    for (int ni = 0; ni < 2; ni++)
#pragma unroll
      for (int e = 0; e < 16; e++) acc[mi][ni][e] = 0.0f;

  auto STAGE = [&](int k0, int s) {
    async16(&A[(size_t)(m0 + sr) * 1024 + k0 + scs],       &As[s][sr * 32 + scl]);
    async16(&A[(size_t)(m0 + 64 + sr) * 1024 + k0 + scs],  &As[s][(64 + sr) * 32 + scl]);
    async16(&Wt[(size_t)(n0 + sr) * 1024 + k0 + scs],      &Bs[s][sr * 32 + scl]);
    async16(&Wt[(size_t)(n0 + 64 + sr) * 1024 + k0 + scs], &Bs[s][(64 + sr) * 32 + scl]);
  };

  STAGE(0, 0);
  const int NK = 1024 / 32;  // 32
  for (int k = 0; k < NK; k++) {
    if (k + 1 < NK) {
      STAGE((k + 1) * 32, (k + 1) % 3);
      // drain stage(k) (and older); stage(k+1)'s 4 loads stay in flight
      asm volatile("s_waitcnt vmcnt(4)" ::: "memory");
    } else {
      asm volatile("s_waitcnt vmcnt(0)" ::: "memory");
    }
    __builtin_amdgcn_s_barrier();
    __builtin_amdgcn_sched_barrier(0);
    const bf16* as = &As[k % 3][0];
    const bf16* bs = &Bs[k % 3][0];
#pragma unroll
    for (int kk = 0; kk < 2; kk++) {
      const int ch = ((kk * 2 + half) ^ csw) * 8;  // de-swizzled chunk offset
      bf16x8 af[2], bfr[2];
#pragma unroll
      for (int mi = 0; mi < 2; mi++)
        af[mi] = *(const bf16x8*)&as[(wm + mi * 32 + col) * 32 + ch];
#pragma unroll
      for (int ni = 0; ni < 2; ni++)
        bfr[ni] = *(const bf16x8*)&bs[(wn + ni * 32 + col) * 32 + ch];
#pragma unroll
      for (int mi = 0; mi < 2; mi++)
#pragma unroll
        for (int ni = 0; ni < 2; ni++)
          acc[mi][ni] = __builtin_amdgcn_mfma_f32_32x32x16_bf16(af[mi], bfr[ni], acc[mi][ni], 0, 0, 0);
    }
  }
  // 32x32 C/D layout: col = lane&31, row = (reg&3) + 8*(reg>>2) + 4*(lane>>5)
#pragma unroll
  for (int ni = 0; ni < 2; ni++) {
    int colg = n0 + wn + ni * 32 + col;
    float bv = bias[colg];
#pragma unroll
    for (int mi = 0; mi < 2; mi++) {
      int rbase = m0 + wm + mi * 32 + half * 4;
      if (transv) {
#pragma unroll
        for (int g = 0; g < 4; g++) {
          int key0 = rbase + g * 8;
          int bb = key0 >> 11, key = key0 & 2047;
          bf16x4 v4;
#pragma unroll
          for (int r = 0; r < 4; r++) v4[r] = (bf16)(acc[mi][ni][g * 4 + r] + bv);
          *(bf16x4*)&((bf16*)C)[(size_t)bb * (DD * (size_t)LL) + (size_t)colg * LL + key] = v4;
        }
      } else {
#pragma unroll
        for (int g = 0; g < 4; g++)
#pragma unroll
          for (int r = 0; r < 4; r++)
            C[(size_t)(rbase + g * 8 + r) * 1024 + colg] = (TC)((acc[mi][ni][g * 4 + r] + bv) * scale);
      }
    }
  }
}

// Fused Q/K/V projection: grid = 3 << shift; which = bid >> shift.
// XCD-bijective swizzle within each GEMM's block range.
__global__ __launch_bounds__(256) void qkv_gemm32(
    const bf16* __restrict__ Xq, const bf16* __restrict__ Xkv,
    const bf16* __restrict__ Wtq, const bf16* __restrict__ Wtk, const bf16* __restrict__ Wtv,
    const float* __restrict__ bq, const float* __restrict__ bk, const float* __restrict__ bv,
    bf16* __restrict__ Qp, bf16* __restrict__ Kp, bf16* __restrict__ VtG, int shift)
{
  const int bid = blockIdx.x;
  const int which = bid >> shift;
  const int bx0 = bid & ((1 << shift) - 1);
  const int q = (1 << shift) >> 3;
  const int bx = (bx0 & 7) * q + (bx0 >> 3);   // XCD-contiguous tm ranges
  if (which == 0)      gemm_body32<bf16>(bx, Xq,  Wtq, bq, Qp,  QSCALE, 0);
  else if (which == 1) gemm_body32<bf16>(bx, Xkv, Wtk, bk, Kp,  1.0f,   0);
  else                 gemm_body32<bf16>(bx, Xkv, Wtv, bv, VtG, 1.0f,   1);
}

// ---------------------------------------------------------------------------
// out GEMM (round-6 proven): 128x64 tile, BK=32, 16x16x32 MFMAs, 3-slot
// counted-vmcnt pipeline (36 KB).
// ---------------------------------------------------------------------------
__global__ __launch_bounds__(256) void out_gemm(
    const bf16* __restrict__ A, const bf16* __restrict__ Wt,
    const float* __restrict__ bias, float* __restrict__ C)
{
  __shared__ bf16 As[3][128 * 32];
  __shared__ bf16 Bs[3][64 * 32];

  const int bid = blockIdx.x;
  const int qs = gridDim.x >> 3;
  const int bx = (bid & 7) * qs + (bid >> 3);  // XCD-bijective swizzle
  const int tm = bx >> 4, tn = bx & 15;
  const int m0 = tm * 128, n0 = tn * 64;
  const int t = threadIdx.x;
  const int w = t >> 6, l = t & 63;
  const int q = l >> 4, i = l & 15;
  const int wm = (w >> 1) * 64, wn = (w & 1) * 32;
  const int sr  = t >> 2;
  const int scl = (t & 3) * 8;
  const int scs = (((t & 3) ^ ((t >> 3) & 3)) * 8);
  const int isw = (i >> 1) & 3;

  const floatx4 zero = {0.f, 0.f, 0.f, 0.f};
  floatx4 acc[4][2];
#pragma unroll
  for (int mi = 0; mi < 4; mi++)
#pragma unroll
    for (int ni = 0; ni < 2; ni++) acc[mi][ni] = zero;

  auto STAGE = [&](int k0, int s) {
    async16(&A[(size_t)(m0 + sr) * 1024 + k0 + scs],       &As[s][sr * 32 + scl]);
    async16(&A[(size_t)(m0 + 64 + sr) * 1024 + k0 + scs],  &As[s][(64 + sr) * 32 + scl]);
    async16(&Wt[(size_t)(n0 + sr) * 1024 + k0 + scs],      &Bs[s][sr * 32 + scl]);
  };

  STAGE(0, 0);
  const int NK = 1024 / 32;
  for (int k = 0; k < NK; k++) {
    if (k + 1 < NK) {
      STAGE((k + 1) * 32, (k + 1) % 3);
      asm volatile("s_waitcnt vmcnt(3)" ::: "memory");
    } else {
      asm volatile("s_waitcnt vmcnt(0)" ::: "memory");
    }
    __builtin_amdgcn_s_barrier();
    __builtin_amdgcn_sched_barrier(0);
    const bf16* as = &As[k % 3][0];
    const bf16* bs = &Bs[k % 3][0];
    const int ch = (q ^ isw) * 8;
    bf16x8 af[4], bfr[2];
#pragma unroll
    for (int mi = 0; mi < 4; mi++)
      af[mi] = *(const bf16x8*)&as[(wm + mi * 16 + i) * 32 + ch];
#pragma unroll
    for (int ni = 0; ni < 2; ni++)
      bfr[ni] = *(const bf16x8*)&bs[(wn + ni * 16 + i) * 32 + ch];
#pragma unroll
    for (int mi = 0; mi < 4; mi++)
#pragma unroll
      for (int ni = 0; ni < 2; ni++)
        acc[mi][ni] = __builtin_amdgcn_mfma_f32_16x16x32_bf16(af[mi], bfr[ni], acc[mi][ni], 0, 0, 0);
  }
#pragma unroll
  for (int ni = 0; ni < 2; ni++) {
    int colg = n0 + wn + ni * 16 + i;
    float bv = bias[colg];
#pragma unroll
    for (int mi = 0; mi < 4; mi++) {
      int row = m0 + wm + mi * 16 + q * 4;
#pragma unroll
      for (int r = 0; r < 4; r++)
        C[(size_t)(row + r) * 1024 + colg] = acc[mi][ni][r] + bv;
    }
  }
}

// ---------------------------------------------------------------------------
// Flash attention v7: in-block SPLIT-K for true 4 waves/SIMD.
// 512 threads = 2 key-groups x 4 waves; group kg handles tiles kg*16..+15
// (keys kg*1024..+1023) over its own private 2-slot K/V double buffer.
// Fixed-max softmax (log2 units, no running max) makes split-K exact:
// partial oacc/psum simply add; f32 combine via LDS at the end.
// Grid = (N/128)*(B*H) = 512 -> 2 blocks/CU x 8 waves = 16 waves/CU
// (v5/v6 were stuck at 8 waves/CU: total work = 2048 waves of 32 qrows).
// Schedule/iter: barrier(implicit vmcnt0 drains own stage) -> STAGE(T+1)
// (a full compute phase to land; writes slot of T-1 whose readers finished
// pre-barrier) -> QK -> softmax -> PV. Bias lives in LDS (no global loads
// in-loop). 72 KB LDS/block.
// ---------------------------------------------------------------------------
__global__ __launch_bounds__(512, 4) void attn_kernel(
    const bf16* __restrict__ Q, const bf16* __restrict__ K,
    const bf16* __restrict__ Vt, const float* __restrict__ biasF,
    bf16* __restrict__ O, int hbits)
{
  __shared__ __align__(16) char smem[73728];   // K 32K | V 32K | bias 8K
  bf16* KVl = (bf16*)smem;
  float* biasLds = (float*)(smem + 65536);

  const int bid = blockIdx.x;
  const int qt = bid >> hbits;
  const int hb = bid & ((1 << hbits) - 1);
  const int h  = (hbits == 5) ? (hb >> 1) : hb;
  const int b  = (hbits == 5) ? (hb & 1) : 0;
  const int t = threadIdx.x;
  const int w = t >> 6, lane = t & 63;
  const int kg = w >> 2;               // key-group 0/1
  const int wi = w & 3;                // wave within group
  const int col = lane & 31;           // qrow within wave / MFMA col
  const int hi  = lane >> 5;
  const int lsw = lane & 7;            // fragment de-swizzle key

  const bf16* Qb = Q  + (size_t)b * (NN * DD) + h * HDD;
  const bf16* Kb = K  + (size_t)b * (LL * DD) + h * HDD;
  const bf16* Vb = Vt + (size_t)b * (DD * (size_t)LL) + (size_t)(h * HDD) * LL;
  const float* biasFb = biasF + b * LL;

  const int qrow = qt * 128 + wi * 32;

  // Q fragment: B[col=qrow][k=d], k = dc*16 + hi*8 + e
  bf16x8 qfrag[4];
#pragma unroll
  for (int dc = 0; dc < 4; dc++)
    qfrag[dc] = *(const bf16x8*)&Qb[(size_t)(qrow + col) * DD + dc * 16 + hi * 8];

  floatx16 oacc[2];
#pragma unroll
  for (int db = 0; db < 2; db++)
#pragma unroll
    for (int e = 0; e < 16; e++) oacc[db][e] = 0.0f;
  float psum = 0.0f;

  // bias -> LDS (512 threads x 1 float4 = 2048 floats)
  *(floatx4*)&biasLds[t * 4] = *(const floatx4*)&biasFb[t * 4];

  // staging indices within this group's 256 threads
  const int tl  = t & 255;
  const int sr  = tl >> 3;                      // dest row 0..31
  const int scl = (tl & 7) * 8;                 // linear LDS chunk (elems)
  const int scs = ((tl & 7) ^ (sr & 7)) * 8;    // swizzled global chunk

  auto STAGE = [&](int tile, int slot) {        // tile: global 0..31
    const int k0 = tile * 64;
    bf16* Kd = KVl + (kg * 2 + slot) * 4096;
    bf16* Vd = KVl + 16384 + (kg * 2 + slot) * 4096;
    async16(&Kb[(size_t)(k0 + sr) * DD + scs],      Kd + sr * 64 + scl);
    async16(&Kb[(size_t)(k0 + sr + 32) * DD + scs], Kd + (sr + 32) * 64 + scl);
    async16(&Vb[(size_t)sr * LL + k0 + scs],        Vd + sr * 64 + scl);
    async16(&Vb[(size_t)(sr + 32) * LL + k0 + scs], Vd + (sr + 32) * 64 + scl);
  };

  // prologue: stage this group's tile 0 into slot 0
  STAGE(kg * 16, 0);

  bf16x8 pfp[4];
  floatx16 sacc[2];

  const int NTg = 16;
  for (int i = 0; i < NTg; i++) {
    const int T = kg * 16 + i;
    const int slot = i & 1;
    // __syncthreads drains vmcnt(0): own group's stage of T has landed, and
    // all waves' compute of T-1 (reader of the slot STAGE below overwrites)
    // completed before this barrier.
    __syncthreads();
    if (i + 1 < NTg) STAGE(T + 1, (i + 1) & 1);

    const bf16* Kc = KVl + (kg * 2 + slot) * 4096;
    const bf16* Vc = KVl + 16384 + (kg * 2 + slot) * 4096;

    // S^T = K·Q^T + maskbias (bias C-init from LDS)
    const int kn = T * 64;
#pragma unroll
    for (int kb = 0; kb < 2; kb++)
#pragma unroll
      for (int gg = 0; gg < 4; gg++) {
        floatx4 pbv = *(const floatx4*)&biasLds[kn + kb * 32 + gg * 8 + hi * 4];
#pragma unroll
        for (int rr = 0; rr < 4; rr++) sacc[kb][gg * 4 + rr] = pbv[rr];
      }
    __builtin_amdgcn_s_setprio(1);
#pragma unroll
    for (int kb = 0; kb < 2; kb++)
#pragma unroll
      for (int dc = 0; dc < 4; dc++) {
        bf16x8 kf = *(const bf16x8*)&Kc[(kb * 32 + col) * 64 + ((dc * 2 + hi) ^ lsw) * 8];
        sacc[kb] = __builtin_amdgcn_mfma_f32_32x32x16_bf16(kf, qfrag[dc], sacc[kb], 0, 0, 0);
      }
    __builtin_amdgcn_s_setprio(0);

    // softmax (fixed-max, log2 units) -> PV B-fragments (in-register transpose)
#pragma unroll
    for (int kb = 0; kb < 2; kb++)
#pragma unroll
      for (int hh = 0; hh < 2; hh++) {
        float pv[8];
#pragma unroll
        for (int e = 0; e < 8; e++) {
          float p = __builtin_amdgcn_exp2f(fminf(sacc[kb][hh * 8 + e], PCLAMP));
          psum += p;
          pv[e] = p;
        }
        unsigned a0 = cvtpk(pv[0], pv[1]);
        unsigned a1 = cvtpk(pv[2], pv[3]);
        unsigned b0 = cvtpk(pv[4], pv[5]);
        unsigned b1 = cvtpk(pv[6], pv[7]);
        plswap(a0, b0);
        plswap(a1, b1);
        pfp[kb * 2 + hh] = mk_frag(a0, a1, b0, b1);
      }

    // O^T += V^T · P^T
    __builtin_amdgcn_s_setprio(1);
#pragma unroll
    for (int db = 0; db < 2; db++)
#pragma unroll
      for (int kc = 0; kc < 4; kc++) {
        bf16x8 vf = *(const bf16x8*)&Vc[(db * 32 + col) * 64 + ((kc * 2 + hi) ^ lsw) * 8];
        oacc[db] = __builtin_amdgcn_mfma_f32_32x32x16_bf16(vf, pfp[kc], oacc[db], 0, 0, 0);
      }
    __builtin_amdgcn_s_setprio(0);
  }

  // ---- split-K combine (f32 through LDS; pad-33 rows -> conflict-free) ----
  __syncthreads();   // all compute done; KV area free for scratch
  float* sOacc = (float*)smem;                       // [4*64][33]
  float* sPsum = (float*)(smem + 4 * 64 * 33 * 4);   // 256 floats
  if (kg == 1) {
    const int base = (wi * 64 + lane) * 33;
#pragma unroll
    for (int db = 0; db < 2; db++)
#pragma unroll
      for (int e = 0; e < 16; e++)
        sOacc[base + db * 16 + e] = oacc[db][e];
    sPsum[wi * 64 + lane] = psum;
  }
  __syncthreads();
  if (kg == 0) {
    const int base = (wi * 64 + lane) * 33;
#pragma unroll
    for (int db = 0; db < 2; db++)
#pragma unroll
      for (int e = 0; e < 16; e++)
        oacc[db][e] += sOacc[base + db * 16 + e];
    psum += sPsum[wi * 64 + lane];
    // lanes l and l+32 share qrow and jointly hold complementary key rows
    psum += __shfl_xor(psum, 32, 64);
    float inv = 1.0f / fmaxf(psum, 1e-30f);

    bf16* Ob = O + (size_t)b * (NN * DD) + h * HDD;
#pragma unroll
    for (int db = 0; db < 2; db++)
#pragma unroll
      for (int gg = 0; gg < 4; gg++) {
        bf16x4 v4;
#pragma unroll
        for (int rr = 0; rr < 4; rr++) v4[rr] = (bf16)(oacc[db][gg * 4 + rr] * inv);
        *(bf16x4*)&Ob[(size_t)(qrow + col) * DD + db * 32 + gg * 8 + hi * 4] = v4;
      }
  }
}

// ---------------------------------------------------------------------------
extern "C" void kernel_launch(void* const* d_in, const int* in_sizes, int n_in,
                              void* d_out, int out_size, void* d_ws, size_t ws_size,
                              hipStream_t stream)
{
  const float* x_q  = (const float*)d_in[0];
  const float* x_kv = (const float*)d_in[1];
  const void*  pad  = d_in[2];
  const float* wq = (const float*)d_in[3];
  const float* bq = (const float*)d_in[4];
  const float* wk = (const float*)d_in[5];
  const float* bk = (const float*)d_in[6];
  const float* wv = (const float*)d_in[7];
  const float* bv = (const float*)d_in[8];
  const float* wo = (const float*)d_in[9];
  const float* bo = (const float*)d_in[10];
  float* out = (float*)d_out;

  char* ws = (char*)d_ws;
  const size_t MB = (size_t)1 << 20;
  const size_t fullElems = (size_t)BB * NN * DD;  // 4M
  const size_t batchElems = (size_t)NN * DD;      // 2M

  if (ws_size >= 49 * MB) {
    bf16* Xqb   = (bf16*)(ws);            // 8 MB, reused as Op after Q-GEMM
    bf16* Xkvb  = (bf16*)(ws + 8 * MB);
    bf16* Wtq   = (bf16*)(ws + 16 * MB);
    bf16* Wtk   = (bf16*)(ws + 18 * MB);
    bf16* Wtv   = (bf16*)(ws + 20 * MB);
    bf16* Wto   = (bf16*)(ws + 22 * MB);
    bf16* Qp    = (bf16*)(ws + 24 * MB);
    bf16* Kp    = (bf16*)(ws + 32 * MB);
    bf16* VtG   = (bf16*)(ws + 40 * MB);
    float* biasF = (float*)(ws + 48 * MB);  // 16 KB
    bf16* Op    = Xqb;

    prep_kernel<<<5121, 256, 0, stream>>>(x_q, x_kv, Xqb, Xkvb, 4096, (int)fullElems,
                                          wq, wk, wv, wo, Wtq, Wtk, Wtv, Wto,
                                          (const unsigned*)pad, biasF);
    qkv_gemm32<<<768, 256, 0, stream>>>(Xqb, Xkvb, Wtq, Wtk, Wtv, bq, bk, bv, Qp, Kp, VtG, 8);
    attn_kernel<<<512, 512, 0, stream>>>(Qp, Kp, VtG, biasF, Op, 5);
    out_gemm<<<512, 256, 0, stream>>>(Op, Wto, bo, out);
  } else {
    bf16* Wtq   = (bf16*)(ws);
    bf16* Wtk   = (bf16*)(ws + 2 * MB);
    bf16* Wtv   = (bf16*)(ws + 4 * MB);
    bf16* Wto   = (bf16*)(ws + 6 * MB);
    bf16* Xqb   = (bf16*)(ws + 8 * MB);   // 4 MB, reused as Op
    bf16* Xkvb  = (bf16*)(ws + 12 * MB);
    bf16* Qp    = (bf16*)(ws + 16 * MB);
    bf16* Kp    = (bf16*)(ws + 20 * MB);
    bf16* VtG   = (bf16*)(ws + 24 * MB);
    float* biasF = (float*)(ws + 28 * MB);
    bf16* Op    = Xqb;

    for (int b = 0; b < BB; b++) {
      if (b == 0)
        prep_kernel<<<3073, 256, 0, stream>>>(x_q, x_kv, Xqb, Xkvb, 2048, (int)batchElems,
                                              wq, wk, wv, wo, Wtq, Wtk, Wtv, Wto,
                                              (const unsigned*)pad, biasF);
      else
        prep_kernel<<<2048, 256, 0, stream>>>(x_q + b * batchElems, x_kv + b * batchElems,
                                              Xqb, Xkvb, 2048, (int)batchElems,
                                              wq, wk, wv, wo, Wtq, Wtk, Wtv, Wto,
                                              (const unsigned*)pad, biasF);
      qkv_gemm32<<<384, 256, 0, stream>>>(Xqb, Xkvb, Wtq, Wtk, Wtv, bq, bk, bv, Qp, Kp, VtG, 7);
      attn_kernel<<<256, 512, 0, stream>>>(Qp, Kp, VtG, biasF + b * LL, Op, 4);
      out_gemm<<<256, 256, 0, stream>>>(Op, Wto, bo, out + b * batchElems);
    }
  }
}